// Round 1
// baseline (279.260 us; speedup 1.0000x reference)
//
#include <hip/hip_runtime.h>
#include <hip/hip_bf16.h>
#include <cstdint>
#include <cstddef>

// Problem constants
#define B_  4
#define S_  2048
#define D_  1024
#define H_  16
#define HD_ 64

typedef _Float16 half8  __attribute__((ext_vector_type(8)));
typedef _Float16 half4v __attribute__((ext_vector_type(4)));
typedef _Float16 half2v __attribute__((ext_vector_type(2)));
typedef float    f32x4  __attribute__((ext_vector_type(4)));
typedef unsigned int uint2v __attribute__((ext_vector_type(2)));
typedef unsigned int uint4v __attribute__((ext_vector_type(4)));

// async global->LDS, 16B per lane. LDS dest = wave-uniform base + lane*16.
__device__ __forceinline__ void async_copy16(const void* g, void* l) {
    __builtin_amdgcn_global_load_lds(
        (const __attribute__((address_space(1))) unsigned int*)g,
        (__attribute__((address_space(3))) unsigned int*)l,
        16, 0, 0);
}

__device__ __forceinline__ half8 hscale8(half8 v, _Float16 s) {
    #pragma unroll
    for (int i = 0; i < 8; ++i) v[i] *= s;
    return v;
}

// RNE f32x2 -> packed f16x2 (identical numerics to scalar (_Float16) casts)
__device__ __forceinline__ unsigned int pack2(float a, float b) {
    half2v h = { (_Float16)a, (_Float16)b };
    return __builtin_bit_cast(unsigned int, h);
}

// ---------------- prep kernels ----------------

__global__ void cast_x_kernel(const float4* __restrict__ in, half4v* __restrict__ out, int n4) {
    int i = blockIdx.x * 256 + threadIdx.x;
    if (i < n4) {
        float4 v = in[i];
        half4v h = { (_Float16)v.x, (_Float16)v.y, (_Float16)v.z, (_Float16)v.w };
        out[i] = h;
    }
}

// 4x fused: W [K=D][N=D] f32 row-major -> Wt [N][K] f16 row-major
__global__ void transpose_cast4_kernel(
    const float* __restrict__ W0, const float* __restrict__ W1,
    const float* __restrict__ W2, const float* __restrict__ W3,
    _Float16* __restrict__ T0, _Float16* __restrict__ T1,
    _Float16* __restrict__ T2, _Float16* __restrict__ T3)
{
    __shared__ float tile[32][33];
    const float* Wsel[4] = { W0, W1, W2, W3 };
    _Float16*    Tsel[4] = { T0, T1, T2, T3 };
    const float* W  = Wsel[blockIdx.z];
    _Float16*    Wt = Tsel[blockIdx.z];
    const int bn = blockIdx.x * 32, bk = blockIdx.y * 32;
    const int tx = threadIdx.x, ty = threadIdx.y;  // 32x8
    #pragma unroll
    for (int i = 0; i < 32; i += 8)
        tile[ty + i][tx] = W[(size_t)(bk + ty + i) * D_ + bn + tx];
    __syncthreads();
    #pragma unroll
    for (int i = 0; i < 32; i += 8)
        Wt[(size_t)(bn + ty + i) * D_ + bk + tx] = (_Float16)tile[tx][ty + i];
}

// ---------------- GEMM: C = relu(A @ Bt^T + bias) ----------------
// A [M][K] f16, Bt [N][K] f16.
// OUT_MODE: 0 = f32 [M][N] to C0;
//           3 = fused QKV: col segment 0->Q f16 [M][1024] (C0), 1->K f16 (C1),
//               2->V^T per head [(b*16+h)][hd][s] (C2); bias b0/b1/b2 per segment.
// 128x128 tile, BK=64, 256 threads = 4 waves (2x2 of 64x64).
// LDS XOR-swizzled: LDS(row, chunk c) holds global chunk c ^ (row&7) (chunk = 16B).
template<int OUT_MODE>
__global__ __launch_bounds__(256, 2) void gemm_bt_kernel(
    const _Float16* __restrict__ A, const _Float16* __restrict__ Bt,
    const float* __restrict__ b0, const float* __restrict__ b1,
    const float* __restrict__ b2,
    void* __restrict__ C0, void* __restrict__ C1, void* __restrict__ C2,
    int M, int N, int K)
{
    __shared__ _Float16 As[128 * 64];
    __shared__ _Float16 Bs[128 * 64];
    const int tid  = threadIdx.x;
    const int wid  = tid >> 6, lane = tid & 63;
    const int lr   = lane & 15, lq = lane >> 4;
    const int m0   = blockIdx.x * 128, n0 = blockIdx.y * 128;
    const int wm   = (wid >> 1) * 64, wn = (wid & 1) * 64;
    const int srow = tid >> 3;                        // 0..31
    const int csw  = ((tid & 7) ^ (srow & 7)) * 8;    // swizzled source col (halfs)

    f32x4 acc[4][4] = {};

    for (int k0 = 0; k0 < K; k0 += 64) {
        __syncthreads();
        #pragma unroll
        for (int i = 0; i < 4; ++i) {
            async_copy16(A  + (size_t)(m0 + i * 32 + srow) * K + k0 + csw,
                         (char*)As + (i * 256 + wid * 64) * 16);
            async_copy16(Bt + (size_t)(n0 + i * 32 + srow) * K + k0 + csw,
                         (char*)Bs + (i * 256 + wid * 64) * 16);
        }
        __syncthreads();
        #pragma unroll
        for (int ks = 0; ks < 2; ++ks) {
            half8 af[4], bf[4];
            #pragma unroll
            for (int t = 0; t < 4; ++t) {
                af[t] = *(const half8*)(As + (wm + t * 16 + lr) * 64 + (((ks * 4 + lq) ^ (lr & 7)) * 8));
                bf[t] = *(const half8*)(Bs + (wn + t * 16 + lr) * 64 + (((ks * 4 + lq) ^ (lr & 7)) * 8));
            }
            #pragma unroll
            for (int mt = 0; mt < 4; ++mt)
                #pragma unroll
                for (int nt = 0; nt < 4; ++nt)
                    acc[mt][nt] = __builtin_amdgcn_mfma_f32_16x16x32_f16(
                        af[mt], bf[nt], acc[mt][nt], 0, 0, 0);
        }
    }

    // n-segment is uniform per block (128 | 1024)
    const int seg = (OUT_MODE == 3) ? (n0 >> 10) : 0;
    const float* bp = (OUT_MODE == 3) ? (seg == 0 ? b0 : (seg == 1 ? b1 : b2)) : b0;

    #pragma unroll
    for (int mt = 0; mt < 4; ++mt) {
        const int row = m0 + wm + mt * 16 + lq * 4;   // + r
        #pragma unroll
        for (int nt = 0; nt < 4; ++nt) {
            const int col = n0 + wn + nt * 16 + lr;
            const int cl  = (OUT_MODE == 3) ? (col & 1023) : col;
            const float bb = bp[cl];
            if (OUT_MODE == 3 && seg == 2) {
                // V^T per head: [(b*16+h)][hd][s]; 4 consecutive s -> one 8B store
                const int b = row >> 11, sq = row & 2047;
                const int h = cl >> 6, hd = cl & 63;
                half4v o;
                #pragma unroll
                for (int r = 0; r < 4; ++r) {
                    float v = acc[mt][nt][r] + bb;
                    o[r] = (_Float16)(v > 0.0f ? v : 0.0f);
                }
                *(half4v*)((_Float16*)C2 +
                           ((size_t)(b * 16 + h) * 64 + hd) * S_ + sq) = o;
            } else if (OUT_MODE == 3) {
                _Float16* dst = (_Float16*)(seg ? C1 : C0);
                #pragma unroll
                for (int r = 0; r < 4; ++r) {
                    float v = acc[mt][nt][r] + bb;
                    dst[(size_t)(row + r) * 1024 + cl] = (_Float16)(v > 0.0f ? v : 0.0f);
                }
            } else {
                #pragma unroll
                for (int r = 0; r < 4; ++r) {
                    float v = acc[mt][nt][r] + bb;
                    ((float*)C0)[(size_t)(row + r) * N + col] = v > 0.0f ? v : 0.0f;
                }
            }
        }
    }
}

// ---------------- flash attention (in-register P, 2 frags/wave, 1024 blocks) ----------------
// R9 was latency-bound: 512 blocks = exactly 2 blocks/CU (grid-limited), and P
// round-tripped through 32 KB of LDS (4x ds_write_b64 + 2x ds_read_b128 +
// lgkmcnt(0) serialization + bank conflicts) purely for layout conversion.
// Now: QK^T output (lane lr=q, 16 strided k) is converted to the PV A-operand
// layout (k = 32ks+8lq+j) IN REGISTERS via gfx950 permlane swaps:
//   d0,d2 = permlane16_swap(permlane32_swap(pk[2ks][0], pk[2ks+1][0]))
//   d1,d3 = permlane16_swap(permlane32_swap(pk[2ks][1], pk[2ks+1][1]))
// (verified per-element: reader lq needs k in [32ks+8lq,+8), held by lanes
//  2(lq&1), 2(lq&1)+1 at t=2ks+(lq>>1); the swap net delivers [x0,x2,z0,z2].)
// LDS drops 64->32 KB, so grid doubles: 1024 blocks (16/head, balanced pairs
// {t, 31-t} of 64-row q tiles, 2 frags/wave, 33 frag-units/wave for every t)
// -> 4 blocks/CU. f16 conversion stays RNE (pack2) = bit-identical numerics.
__global__ __launch_bounds__(256, 4) void attn_kernel(
    const _Float16* __restrict__ Qg, const _Float16* __restrict__ Kg,
    const _Float16* __restrict__ Vtg, _Float16* __restrict__ Y)
{
    __shared__ _Float16 Ks[2][64 * 64];      // [key][hd], swizzled chunks
    __shared__ _Float16 Vt[2][64 * 64];      // [hd][key], swizzled chunks

    // XCD swizzle: a head's 16 blocks share (i&7) -> same XCD L2 caches its K/V.
    const int i  = blockIdx.x;                 // 0..1023
    const int bh = ((i & 7) << 3) | (i >> 7);  // 0..63
    const int tp = (i >> 3) & 15;              // pair index 0..15
    const int b  = bh >> 4, h = bh & 15;
    const int tid = threadIdx.x, wid = tid >> 6, lane = tid & 63;
    const int lr = lane & 15, lq = lane >> 4;

    const size_t base  = ((size_t)b * S_) * D_ + (size_t)h * HD_;   // Q/K/Y
    const _Float16* Vh = Vtg + (size_t)bh * 64 * S_;                // V^T head

    const int srow = tid >> 3;                       // 0..31
    const int csw  = ((tid & 7) ^ (srow & 7)) * 8;   // swizzled SOURCE col (halfs)

    // 2 fragments per wave: lo tile rows [64*tp, +64), hi tile rows [2048-64*(tp+1), +64)
    const int qb[2] = { 64 * tp + 16 * wid, 2048 - 64 * (tp + 1) + 16 * wid };
    const int dk[2] = { tp, 31 - tp };               // diag k-tile per frag
    const int nIter = 32 - tp;

    // Q fragments (B-operand rows [q][hd]) pre-scaled by log2(e)/8
    half8 aq[2][2];
    #pragma unroll
    for (int f = 0; f < 2; ++f) {
        const _Float16* qp = Qg + base + (size_t)(qb[f] + lr) * D_;
        aq[f][0] = hscale8(*(const half8*)(qp + lq * 8),      (_Float16)0.18033688f);
        aq[f][1] = hscale8(*(const half8*)(qp + 32 + lq * 8), (_Float16)0.18033688f);
    }

    float lsum[2] = {};
    f32x4 O[2][4] = {};
    half8 apf[2][2];   // in-register P fragments (PV A-operand)

    auto issue_tile = [&](int kb) {
        const int bufi = kb & 1;
        #pragma unroll
        for (int ii = 0; ii < 2; ++ii) {
            async_copy16(Kg + base + (size_t)(kb * 64 + ii * 32 + srow) * D_ + csw,
                         (char*)Ks[bufi] + (ii * 256 + wid * 64) * 16);
            async_copy16(Vh + (size_t)(ii * 32 + srow) * S_ + kb * 64 + csw,
                         (char*)Vt[bufi] + (ii * 256 + wid * 64) * 16);
        }
    };

    issue_tile(0);

    for (int kb = 0; kb < nIter; ++kb) {
        const int cur = kb & 1;
        __syncthreads();   // buf[cur] loads done; all waves done with buf[cur] from kb-2
        if (kb + 1 < nIter) issue_tile(kb + 1);

        const _Float16* Kc = Ks[cur];
        const _Float16* Vc = Vt[cur];

        // ---- phase 1: read kf once, QK + softmax + in-register P per active frag ----
        half8 kf[2][4];
        #pragma unroll
        for (int ks = 0; ks < 2; ++ks)
            #pragma unroll
            for (int tt = 0; tt < 4; ++tt)
                kf[ks][tt] = *(const half8*)(Kc + (tt * 16 + lr) * 64 + (((ks * 4 + lq) ^ (lr & 7)) * 8));

        #pragma unroll
        for (int f = 0; f < 2; ++f) {
            if (kb > dk[f]) continue;            // frag done (wave-uniform)

            f32x4 sc[4] = {};
            #pragma unroll
            for (int ks = 0; ks < 2; ++ks)
                #pragma unroll
                for (int tt = 0; tt < 4; ++tt)
                    sc[tt] = __builtin_amdgcn_mfma_f32_16x16x32_f16(kf[ks][tt], aq[f][ks], sc[tt], 0, 0, 0);

            const bool diag = (kb == dk[f]);     // wave-uniform
            const int qg = qb[f] + lr;           // this lane's q
            const int kbase = kb * 64 + lq * 4;
            float sum = 0.0f;
            unsigned int pk[4][2];               // pk[t][d]: packed f16x2 of ev
            #pragma unroll
            for (int tt = 0; tt < 4; ++tt) {
                float ev[4];
                #pragma unroll
                for (int r = 0; r < 4; ++r) {
                    // sc in log2 units; 4*log2e = 5.770780, clamp 11*log2e
                    float e = __builtin_amdgcn_exp2f(fminf(sc[tt][r] - 5.770780f, 15.8696f));
                    if (diag)
                        e = (kbase + tt * 16 + r <= qg) ? e : 0.0f;  // causal AFTER exp
                    ev[r] = e;
                    sum += e;
                }
                pk[tt][0] = pack2(ev[0], ev[1]);
                pk[tt][1] = pack2(ev[2], ev[3]);
            }
            lsum[f] += sum;

            // layout exchange within each 4-lane lq-group (rows of 16 lanes):
            // permlane32_swap: a'=[a0,a1,b0,b1], b'=[a2,a3,b2,b3] (16-lane rows)
            // permlane16_swap: a''=[a0,b0,a2,b2], b''=[a1,b1,a3,b3]
            #pragma unroll
            for (int ks = 0; ks < 2; ++ks) {
                uint2v s1 = __builtin_amdgcn_permlane32_swap(pk[2 * ks][0], pk[2 * ks + 1][0], false, false);
                uint2v s2 = __builtin_amdgcn_permlane16_swap(s1[0], s1[1], false, false);
                uint2v u1 = __builtin_amdgcn_permlane32_swap(pk[2 * ks][1], pk[2 * ks + 1][1], false, false);
                uint2v u2 = __builtin_amdgcn_permlane16_swap(u1[0], u1[1], false, false);
                uint4v d = { s2[0], u2[0], s2[1], u2[1] };
                apf[f][ks] = __builtin_bit_cast(half8, d);
            }
        }

        // ---- phase 2: read bv once, PV per active frag (P straight from regs) ----
        half8 bv[2][4];
        #pragma unroll
        for (int ks = 0; ks < 2; ++ks)
            #pragma unroll
            for (int tt = 0; tt < 4; ++tt)
                bv[ks][tt] = *(const half8*)(Vc + (tt * 16 + lr) * 64 + (((ks * 4 + lq) ^ (lr & 7)) * 8));

        #pragma unroll
        for (int f = 0; f < 2; ++f) {
            if (kb > dk[f]) continue;
            #pragma unroll
            for (int ks = 0; ks < 2; ++ks)
                #pragma unroll
                for (int tt = 0; tt < 4; ++tt)
                    O[f][tt] = __builtin_amdgcn_mfma_f32_16x16x32_f16(apf[f][ks], bv[ks][tt], O[f][tt], 0, 0, 0);
        }
    }

    // epilogue: combine lq-group partial sums, then ctx = O/(l+EPS) -> Y f16
    #pragma unroll
    for (int f = 0; f < 2; ++f) {
        float tot = lsum[f];
        tot += __shfl_xor(tot, 16);
        tot += __shfl_xor(tot, 32);          // all 4 copies of q=lr now hold row sum
        const int q0 = qb[f] + lq * 4;
        #pragma unroll
        for (int r = 0; r < 4; ++r) {
            const float inv = 1.0f / (__shfl(tot, lq * 4 + r) + 1e-7f);
            #pragma unroll
            for (int nt = 0; nt < 4; ++nt)
                Y[base + (size_t)(q0 + r) * D_ + nt * 16 + lr] = (_Float16)(O[f][nt][r] * inv);
        }
    }
}

// ---------------- launch ----------------

extern "C" void kernel_launch(void* const* d_in, const int* in_sizes, int n_in,
                              void* d_out, int out_size, void* d_ws, size_t ws_size,
                              hipStream_t stream) {
    const float* x  = (const float*)d_in[0];
    const float* Wq = (const float*)d_in[1];
    const float* bq = (const float*)d_in[2];
    const float* Wk = (const float*)d_in[3];
    const float* bk = (const float*)d_in[4];
    const float* Wv = (const float*)d_in[5];
    const float* bv = (const float*)d_in[6];
    const float* Wo = (const float*)d_in[7];
    const float* bo = (const float*)d_in[8];

    // workspace layout (f16): xh 16MB | 4x Wt 2MB (wtq/wtk/wtv contiguous!) |
    // Q,K,Vt,Y 16MB each => 92.3 MB
    char* ws = (char*)d_ws;
    _Float16* xh  = (_Float16*)ws;
    _Float16* wtq = (_Float16*)(ws + (size_t)16777216);
    _Float16* wtk = wtq + 1048576;
    _Float16* wtv = wtk + 1048576;
    _Float16* wto = wtv + 1048576;
    _Float16* Qh  = (_Float16*)(ws + (size_t)16777216 + 4 * (size_t)2097152);
    _Float16* Kh  = Qh + 8388608;
    _Float16* Vth = Kh + 8388608;
    _Float16* Yh  = Vth + 8388608;
    float* out = (float*)d_out;

    cast_x_kernel<<<8192, 256, 0, stream>>>((const float4*)x, (half4v*)xh, 2097152);
    transpose_cast4_kernel<<<dim3(32, 32, 4), dim3(32, 8), 0, stream>>>(
        Wq, Wk, Wv, Wo, wtq, wtk, wtv, wto);

    // fused QKV GEMM: Bt = [wtq;wtk;wtv] (contiguous), N=3072
    gemm_bt_kernel<3><<<dim3(64, 24), 256, 0, stream>>>(
        xh, wtq, bq, bk, bv, Qh, Kh, Vth, 8192, 3072, 1024);

    attn_kernel<<<1024, 256, 0, stream>>>(Qh, Kh, Vth, Yh);

    gemm_bt_kernel<0><<<dim3(64, 8), 256, 0, stream>>>(
        Yh, wto, bo, bo, bo, out, out, out, 8192, 1024, 1024);
}

// Round 2
// 252.892 us; speedup vs baseline: 1.1043x; 1.1043x over previous
//
#include <hip/hip_runtime.h>
#include <hip/hip_bf16.h>
#include <cstdint>
#include <cstddef>

// Problem constants
#define B_  4
#define S_  2048
#define D_  1024
#define H_  16
#define HD_ 64

typedef _Float16 half8  __attribute__((ext_vector_type(8)));
typedef _Float16 half4v __attribute__((ext_vector_type(4)));
typedef _Float16 half2v __attribute__((ext_vector_type(2)));
typedef float    f32x4  __attribute__((ext_vector_type(4)));
typedef unsigned int uint2v __attribute__((ext_vector_type(2)));
typedef unsigned int uint4v __attribute__((ext_vector_type(4)));

// async global->LDS, 16B per lane. LDS dest = wave-uniform base + lane*16.
__device__ __forceinline__ void async_copy16(const void* g, void* l) {
    __builtin_amdgcn_global_load_lds(
        (const __attribute__((address_space(1))) unsigned int*)g,
        (__attribute__((address_space(3))) unsigned int*)l,
        16, 0, 0);
}

__device__ __forceinline__ half8 hscale8(half8 v, _Float16 s) {
    #pragma unroll
    for (int i = 0; i < 8; ++i) v[i] *= s;
    return v;
}

// RNE f32x2 -> packed f16x2 (identical numerics to scalar (_Float16) casts)
__device__ __forceinline__ unsigned int pack2(float a, float b) {
    half2v h = { (_Float16)a, (_Float16)b };
    return __builtin_bit_cast(unsigned int, h);
}

// ---------------- prep kernels ----------------

__global__ void cast_x_kernel(const float4* __restrict__ in, half4v* __restrict__ out, int n4) {
    int i = blockIdx.x * 256 + threadIdx.x;
    if (i < n4) {
        float4 v = in[i];
        half4v h = { (_Float16)v.x, (_Float16)v.y, (_Float16)v.z, (_Float16)v.w };
        out[i] = h;
    }
}

// 4x fused: W [K=D][N=D] f32 row-major -> Wt [N][K] f16 row-major
__global__ void transpose_cast4_kernel(
    const float* __restrict__ W0, const float* __restrict__ W1,
    const float* __restrict__ W2, const float* __restrict__ W3,
    _Float16* __restrict__ T0, _Float16* __restrict__ T1,
    _Float16* __restrict__ T2, _Float16* __restrict__ T3)
{
    __shared__ float tile[32][33];
    const float* Wsel[4] = { W0, W1, W2, W3 };
    _Float16*    Tsel[4] = { T0, T1, T2, T3 };
    const float* W  = Wsel[blockIdx.z];
    _Float16*    Wt = Tsel[blockIdx.z];
    const int bn = blockIdx.x * 32, bk = blockIdx.y * 32;
    const int tx = threadIdx.x, ty = threadIdx.y;  // 32x8
    #pragma unroll
    for (int i = 0; i < 32; i += 8)
        tile[ty + i][tx] = W[(size_t)(bk + ty + i) * D_ + bn + tx];
    __syncthreads();
    #pragma unroll
    for (int i = 0; i < 32; i += 8)
        Wt[(size_t)(bn + ty + i) * D_ + bk + tx] = (_Float16)tile[tx][ty + i];
}

// ---------------- GEMM: C = relu(A @ Bt^T + bias) ----------------
// A [M][K] f16, Bt [N][K] f16.
// OUT_MODE: 0 = f32 [M][N] to C0;
//           3 = fused QKV: col segment 0->Q f16 [M][1024] (C0), 1->K f16 (C1),
//               2->V^T per head [(b*16+h)][hd][s] (C2); bias b0/b1/b2 per segment.
// 128x128 tile, BK=64, 256 threads = 4 waves (2x2 of 64x64).
// LDS XOR-swizzled: LDS(row, chunk c) holds global chunk c ^ (row&7) (chunk = 16B).
template<int OUT_MODE>
__global__ __launch_bounds__(256, 2) void gemm_bt_kernel(
    const _Float16* __restrict__ A, const _Float16* __restrict__ Bt,
    const float* __restrict__ b0, const float* __restrict__ b1,
    const float* __restrict__ b2,
    void* __restrict__ C0, void* __restrict__ C1, void* __restrict__ C2,
    int M, int N, int K)
{
    __shared__ _Float16 As[128 * 64];
    __shared__ _Float16 Bs[128 * 64];
    const int tid  = threadIdx.x;
    const int wid  = tid >> 6, lane = tid & 63;
    const int lr   = lane & 15, lq = lane >> 4;
    const int m0   = blockIdx.x * 128, n0 = blockIdx.y * 128;
    const int wm   = (wid >> 1) * 64, wn = (wid & 1) * 64;
    const int srow = tid >> 3;                        // 0..31
    const int csw  = ((tid & 7) ^ (srow & 7)) * 8;    // swizzled source col (halfs)

    f32x4 acc[4][4] = {};

    for (int k0 = 0; k0 < K; k0 += 64) {
        __syncthreads();
        #pragma unroll
        for (int i = 0; i < 4; ++i) {
            async_copy16(A  + (size_t)(m0 + i * 32 + srow) * K + k0 + csw,
                         (char*)As + (i * 256 + wid * 64) * 16);
            async_copy16(Bt + (size_t)(n0 + i * 32 + srow) * K + k0 + csw,
                         (char*)Bs + (i * 256 + wid * 64) * 16);
        }
        __syncthreads();
        #pragma unroll
        for (int ks = 0; ks < 2; ++ks) {
            half8 af[4], bf[4];
            #pragma unroll
            for (int t = 0; t < 4; ++t) {
                af[t] = *(const half8*)(As + (wm + t * 16 + lr) * 64 + (((ks * 4 + lq) ^ (lr & 7)) * 8));
                bf[t] = *(const half8*)(Bs + (wn + t * 16 + lr) * 64 + (((ks * 4 + lq) ^ (lr & 7)) * 8));
            }
            #pragma unroll
            for (int mt = 0; mt < 4; ++mt)
                #pragma unroll
                for (int nt = 0; nt < 4; ++nt)
                    acc[mt][nt] = __builtin_amdgcn_mfma_f32_16x16x32_f16(
                        af[mt], bf[nt], acc[mt][nt], 0, 0, 0);
        }
    }

    // n-segment is uniform per block (128 | 1024)
    const int seg = (OUT_MODE == 3) ? (n0 >> 10) : 0;
    const float* bp = (OUT_MODE == 3) ? (seg == 0 ? b0 : (seg == 1 ? b1 : b2)) : b0;

    #pragma unroll
    for (int mt = 0; mt < 4; ++mt) {
        const int row = m0 + wm + mt * 16 + lq * 4;   // + r
        #pragma unroll
        for (int nt = 0; nt < 4; ++nt) {
            const int col = n0 + wn + nt * 16 + lr;
            const int cl  = (OUT_MODE == 3) ? (col & 1023) : col;
            const float bb = bp[cl];
            if (OUT_MODE == 3 && seg == 2) {
                // V^T per head: [(b*16+h)][hd][s]; 4 consecutive s -> one 8B store
                const int b = row >> 11, sq = row & 2047;
                const int h = cl >> 6, hd = cl & 63;
                half4v o;
                #pragma unroll
                for (int r = 0; r < 4; ++r) {
                    float v = acc[mt][nt][r] + bb;
                    o[r] = (_Float16)(v > 0.0f ? v : 0.0f);
                }
                *(half4v*)((_Float16*)C2 +
                           ((size_t)(b * 16 + h) * 64 + hd) * S_ + sq) = o;
            } else if (OUT_MODE == 3) {
                _Float16* dst = (_Float16*)(seg ? C1 : C0);
                #pragma unroll
                for (int r = 0; r < 4; ++r) {
                    float v = acc[mt][nt][r] + bb;
                    dst[(size_t)(row + r) * 1024 + cl] = (_Float16)(v > 0.0f ? v : 0.0f);
                }
            } else {
                #pragma unroll
                for (int r = 0; r < 4; ++r) {
                    float v = acc[mt][nt][r] + bb;
                    ((float*)C0)[(size_t)(row + r) * N + col] = v > 0.0f ? v : 0.0f;
                }
            }
        }
    }
}

// ---------------- flash attention (in-register P, 2 frags/wave, 1024 blocks) ----------------
// R10: R1's launch_bounds(256,4) forced a 128-reg/wave budget -> 64 arch VGPRs
// + massive scratch spill (WRITE_SIZE 16->83 MB, attn 75.6->88.8 us despite
// occupancy 17->34%). The permlane P-conversion itself was correct (bank
// conflicts 2.16M -> 0, passed). Live set is ~140-155 regs (incl AGPR accs),
// so cap at 3 waves/SIMD (170-reg budget): __launch_bounds__(256,3).
// 3 blocks/CU (32 KB LDS each), no spill, no P-LDS round-trip.
// QK^T output (lane lr=q, 16 strided k) -> PV A-operand layout (k=32ks+8lq+j)
// in registers via permlane32_swap + permlane16_swap per 4-lane lq-group.
__global__ __launch_bounds__(256, 3) void attn_kernel(
    const _Float16* __restrict__ Qg, const _Float16* __restrict__ Kg,
    const _Float16* __restrict__ Vtg, _Float16* __restrict__ Y)
{
    __shared__ _Float16 Ks[2][64 * 64];      // [key][hd], swizzled chunks
    __shared__ _Float16 Vt[2][64 * 64];      // [hd][key], swizzled chunks

    // XCD swizzle: a head's 16 blocks share (i&7) -> same XCD L2 caches its K/V.
    const int i  = blockIdx.x;                 // 0..1023
    const int bh = ((i & 7) << 3) | (i >> 7);  // 0..63
    const int tp = (i >> 3) & 15;              // pair index 0..15
    const int b  = bh >> 4, h = bh & 15;
    const int tid = threadIdx.x, wid = tid >> 6, lane = tid & 63;
    const int lr = lane & 15, lq = lane >> 4;

    const size_t base  = ((size_t)b * S_) * D_ + (size_t)h * HD_;   // Q/K/Y
    const _Float16* Vh = Vtg + (size_t)bh * 64 * S_;                // V^T head

    const int srow = tid >> 3;                       // 0..31
    const int csw  = ((tid & 7) ^ (srow & 7)) * 8;   // swizzled SOURCE col (halfs)

    // 2 fragments per wave: lo tile rows [64*tp, +64), hi tile rows [2048-64*(tp+1), +64)
    const int qb[2] = { 64 * tp + 16 * wid, 2048 - 64 * (tp + 1) + 16 * wid };
    const int dk[2] = { tp, 31 - tp };               // diag k-tile per frag
    const int nIter = 32 - tp;

    // Q fragments (B-operand rows [q][hd]) pre-scaled by log2(e)/8
    half8 aq[2][2];
    #pragma unroll
    for (int f = 0; f < 2; ++f) {
        const _Float16* qp = Qg + base + (size_t)(qb[f] + lr) * D_;
        aq[f][0] = hscale8(*(const half8*)(qp + lq * 8),      (_Float16)0.18033688f);
        aq[f][1] = hscale8(*(const half8*)(qp + 32 + lq * 8), (_Float16)0.18033688f);
    }

    float lsum[2] = {};
    f32x4 O[2][4] = {};
    half8 apf[2][2];   // in-register P fragments (PV A-operand)

    auto issue_tile = [&](int kb) {
        const int bufi = kb & 1;
        #pragma unroll
        for (int ii = 0; ii < 2; ++ii) {
            async_copy16(Kg + base + (size_t)(kb * 64 + ii * 32 + srow) * D_ + csw,
                         (char*)Ks[bufi] + (ii * 256 + wid * 64) * 16);
            async_copy16(Vh + (size_t)(ii * 32 + srow) * S_ + kb * 64 + csw,
                         (char*)Vt[bufi] + (ii * 256 + wid * 64) * 16);
        }
    };

    issue_tile(0);

    for (int kb = 0; kb < nIter; ++kb) {
        const int cur = kb & 1;
        __syncthreads();   // buf[cur] loads done; all waves done with buf[cur] from kb-2
        if (kb + 1 < nIter) issue_tile(kb + 1);

        const _Float16* Kc = Ks[cur];
        const _Float16* Vc = Vt[cur];

        // ---- phase 1: read kf once, QK + softmax + in-register P per active frag ----
        half8 kf[2][4];
        #pragma unroll
        for (int ks = 0; ks < 2; ++ks)
            #pragma unroll
            for (int tt = 0; tt < 4; ++tt)
                kf[ks][tt] = *(const half8*)(Kc + (tt * 16 + lr) * 64 + (((ks * 4 + lq) ^ (lr & 7)) * 8));

        #pragma unroll
        for (int f = 0; f < 2; ++f) {
            if (kb > dk[f]) continue;            // frag done (wave-uniform)

            f32x4 sc[4] = {};
            #pragma unroll
            for (int ks = 0; ks < 2; ++ks)
                #pragma unroll
                for (int tt = 0; tt < 4; ++tt)
                    sc[tt] = __builtin_amdgcn_mfma_f32_16x16x32_f16(kf[ks][tt], aq[f][ks], sc[tt], 0, 0, 0);

            const bool diag = (kb == dk[f]);     // wave-uniform
            const int qg = qb[f] + lr;           // this lane's q
            const int kbase = kb * 64 + lq * 4;
            float sum = 0.0f;
            unsigned int pk[4][2];               // pk[t][d]: packed f16x2 of ev
            #pragma unroll
            for (int tt = 0; tt < 4; ++tt) {
                float ev[4];
                #pragma unroll
                for (int r = 0; r < 4; ++r) {
                    // sc in log2 units; 4*log2e = 5.770780, clamp 11*log2e
                    float e = __builtin_amdgcn_exp2f(fminf(sc[tt][r] - 5.770780f, 15.8696f));
                    if (diag)
                        e = (kbase + tt * 16 + r <= qg) ? e : 0.0f;  // causal AFTER exp
                    ev[r] = e;
                    sum += e;
                }
                pk[tt][0] = pack2(ev[0], ev[1]);
                pk[tt][1] = pack2(ev[2], ev[3]);
            }
            lsum[f] += sum;

            // layout exchange within each 4-lane lq-group (rows of 16 lanes):
            // permlane32_swap: a'=[a0,a1,b0,b1], b'=[a2,a3,b2,b3] (16-lane rows)
            // permlane16_swap: a''=[a0,b0,a2,b2], b''=[a1,b1,a3,b3]
            #pragma unroll
            for (int ks = 0; ks < 2; ++ks) {
                uint2v s1 = __builtin_amdgcn_permlane32_swap(pk[2 * ks][0], pk[2 * ks + 1][0], false, false);
                uint2v s2 = __builtin_amdgcn_permlane16_swap(s1[0], s1[1], false, false);
                uint2v u1 = __builtin_amdgcn_permlane32_swap(pk[2 * ks][1], pk[2 * ks + 1][1], false, false);
                uint2v u2 = __builtin_amdgcn_permlane16_swap(u1[0], u1[1], false, false);
                uint4v d = { s2[0], u2[0], s2[1], u2[1] };
                apf[f][ks] = __builtin_bit_cast(half8, d);
            }
        }

        // ---- phase 2: read bv once, PV per active frag (P straight from regs) ----
        half8 bv[2][4];
        #pragma unroll
        for (int ks = 0; ks < 2; ++ks)
            #pragma unroll
            for (int tt = 0; tt < 4; ++tt)
                bv[ks][tt] = *(const half8*)(Vc + (tt * 16 + lr) * 64 + (((ks * 4 + lq) ^ (lr & 7)) * 8));

        #pragma unroll
        for (int f = 0; f < 2; ++f) {
            if (kb > dk[f]) continue;
            #pragma unroll
            for (int ks = 0; ks < 2; ++ks)
                #pragma unroll
                for (int tt = 0; tt < 4; ++tt)
                    O[f][tt] = __builtin_amdgcn_mfma_f32_16x16x32_f16(apf[f][ks], bv[ks][tt], O[f][tt], 0, 0, 0);
        }
    }

    // epilogue: combine lq-group partial sums, then ctx = O/(l+EPS) -> Y f16
    #pragma unroll
    for (int f = 0; f < 2; ++f) {
        float tot = lsum[f];
        tot += __shfl_xor(tot, 16);
        tot += __shfl_xor(tot, 32);          // all 4 copies of q=lr now hold row sum
        const int q0 = qb[f] + lq * 4;
        #pragma unroll
        for (int r = 0; r < 4; ++r) {
            const float inv = 1.0f / (__shfl(tot, lq * 4 + r) + 1e-7f);
            #pragma unroll
            for (int nt = 0; nt < 4; ++nt)
                Y[base + (size_t)(q0 + r) * D_ + nt * 16 + lr] = (_Float16)(O[f][nt][r] * inv);
        }
    }
}

// ---------------- launch ----------------

extern "C" void kernel_launch(void* const* d_in, const int* in_sizes, int n_in,
                              void* d_out, int out_size, void* d_ws, size_t ws_size,
                              hipStream_t stream) {
    const float* x  = (const float*)d_in[0];
    const float* Wq = (const float*)d_in[1];
    const float* bq = (const float*)d_in[2];
    const float* Wk = (const float*)d_in[3];
    const float* bk = (const float*)d_in[4];
    const float* Wv = (const float*)d_in[5];
    const float* bv = (const float*)d_in[6];
    const float* Wo = (const float*)d_in[7];
    const float* bo = (const float*)d_in[8];

    // workspace layout (f16): xh 16MB | 4x Wt 2MB (wtq/wtk/wtv contiguous!) |
    // Q,K,Vt,Y 16MB each => 92.3 MB
    char* ws = (char*)d_ws;
    _Float16* xh  = (_Float16*)ws;
    _Float16* wtq = (_Float16*)(ws + (size_t)16777216);
    _Float16* wtk = wtq + 1048576;
    _Float16* wtv = wtk + 1048576;
    _Float16* wto = wtv + 1048576;
    _Float16* Qh  = (_Float16*)(ws + (size_t)16777216 + 4 * (size_t)2097152);
    _Float16* Kh  = Qh + 8388608;
    _Float16* Vth = Kh + 8388608;
    _Float16* Yh  = Vth + 8388608;
    float* out = (float*)d_out;

    cast_x_kernel<<<8192, 256, 0, stream>>>((const float4*)x, (half4v*)xh, 2097152);
    transpose_cast4_kernel<<<dim3(32, 32, 4), dim3(32, 8), 0, stream>>>(
        Wq, Wk, Wv, Wo, wtq, wtk, wtv, wto);

    // fused QKV GEMM: Bt = [wtq;wtk;wtv] (contiguous), N=3072
    gemm_bt_kernel<3><<<dim3(64, 24), 256, 0, stream>>>(
        xh, wtq, bq, bk, bv, Qh, Kh, Vth, 8192, 3072, 1024);

    attn_kernel<<<1024, 256, 0, stream>>>(Qh, Kh, Vth, Yh);

    gemm_bt_kernel<0><<<dim3(64, 8), 256, 0, stream>>>(
        Yh, wto, bo, bo, bo, out, out, out, 8192, 1024, 1024);
}

// Round 3
// 246.215 us; speedup vs baseline: 1.1342x; 1.0271x over previous
//
#include <hip/hip_runtime.h>
#include <hip/hip_bf16.h>
#include <cstdint>
#include <cstddef>

// Problem constants
#define B_  4
#define S_  2048
#define D_  1024
#define H_  16
#define HD_ 64

typedef _Float16 half8  __attribute__((ext_vector_type(8)));
typedef _Float16 half4v __attribute__((ext_vector_type(4)));
typedef _Float16 half2v __attribute__((ext_vector_type(2)));
typedef float    f32x4  __attribute__((ext_vector_type(4)));
typedef unsigned int uint2v __attribute__((ext_vector_type(2)));
typedef unsigned int uint4v __attribute__((ext_vector_type(4)));

// async global->LDS, 16B per lane. LDS dest = wave-uniform base + lane*16.
__device__ __forceinline__ void async_copy16(const void* g, void* l) {
    __builtin_amdgcn_global_load_lds(
        (const __attribute__((address_space(1))) unsigned int*)g,
        (__attribute__((address_space(3))) unsigned int*)l,
        16, 0, 0);
}

__device__ __forceinline__ half8 hscale8(half8 v, _Float16 s) {
    #pragma unroll
    for (int i = 0; i < 8; ++i) v[i] *= s;
    return v;
}

// RNE f32x2 -> packed f16x2 (identical numerics to scalar (_Float16) casts)
__device__ __forceinline__ unsigned int pack2(float a, float b) {
    half2v h = { (_Float16)a, (_Float16)b };
    return __builtin_bit_cast(unsigned int, h);
}

// ---------------- prep kernels ----------------

__global__ void cast_x_kernel(const float4* __restrict__ in, half4v* __restrict__ out, int n4) {
    int i = blockIdx.x * 256 + threadIdx.x;
    if (i < n4) {
        float4 v = in[i];
        half4v h = { (_Float16)v.x, (_Float16)v.y, (_Float16)v.z, (_Float16)v.w };
        out[i] = h;
    }
}

// 4x fused: W [K=D][N=D] f32 row-major -> Wt [N][K] f16 row-major
__global__ void transpose_cast4_kernel(
    const float* __restrict__ W0, const float* __restrict__ W1,
    const float* __restrict__ W2, const float* __restrict__ W3,
    _Float16* __restrict__ T0, _Float16* __restrict__ T1,
    _Float16* __restrict__ T2, _Float16* __restrict__ T3)
{
    __shared__ float tile[32][33];
    const float* Wsel[4] = { W0, W1, W2, W3 };
    _Float16*    Tsel[4] = { T0, T1, T2, T3 };
    const float* W  = Wsel[blockIdx.z];
    _Float16*    Wt = Tsel[blockIdx.z];
    const int bn = blockIdx.x * 32, bk = blockIdx.y * 32;
    const int tx = threadIdx.x, ty = threadIdx.y;  // 32x8
    #pragma unroll
    for (int i = 0; i < 32; i += 8)
        tile[ty + i][tx] = W[(size_t)(bk + ty + i) * D_ + bn + tx];
    __syncthreads();
    #pragma unroll
    for (int i = 0; i < 32; i += 8)
        Wt[(size_t)(bn + ty + i) * D_ + bk + tx] = (_Float16)tile[tx][ty + i];
}

// ---------------- GEMM: C = relu(A @ Bt^T + bias) ----------------
// A [M][K] f16, Bt [N][K] f16.
// OUT_MODE: 0 = f32 [M][N] to C0;
//           3 = fused QKV: col segment 0->Q f16 [M][1024] (C0), 1->K f16 (C1),
//               2->V^T per head [(b*16+h)][hd][s] (C2); bias b0/b1/b2 per segment.
// 128x128 tile, BK=64, 256 threads = 4 waves (2x2 of 64x64).
// LDS XOR-swizzled: LDS(row, chunk c) holds global chunk c ^ (row&7) (chunk = 16B).
template<int OUT_MODE>
__global__ __launch_bounds__(256, 2) void gemm_bt_kernel(
    const _Float16* __restrict__ A, const _Float16* __restrict__ Bt,
    const float* __restrict__ b0, const float* __restrict__ b1,
    const float* __restrict__ b2,
    void* __restrict__ C0, void* __restrict__ C1, void* __restrict__ C2,
    int M, int N, int K)
{
    __shared__ _Float16 As[128 * 64];
    __shared__ _Float16 Bs[128 * 64];
    const int tid  = threadIdx.x;
    const int wid  = tid >> 6, lane = tid & 63;
    const int lr   = lane & 15, lq = lane >> 4;
    const int m0   = blockIdx.x * 128, n0 = blockIdx.y * 128;
    const int wm   = (wid >> 1) * 64, wn = (wid & 1) * 64;
    const int srow = tid >> 3;                        // 0..31
    const int csw  = ((tid & 7) ^ (srow & 7)) * 8;    // swizzled source col (halfs)

    f32x4 acc[4][4] = {};

    for (int k0 = 0; k0 < K; k0 += 64) {
        __syncthreads();
        #pragma unroll
        for (int i = 0; i < 4; ++i) {
            async_copy16(A  + (size_t)(m0 + i * 32 + srow) * K + k0 + csw,
                         (char*)As + (i * 256 + wid * 64) * 16);
            async_copy16(Bt + (size_t)(n0 + i * 32 + srow) * K + k0 + csw,
                         (char*)Bs + (i * 256 + wid * 64) * 16);
        }
        __syncthreads();
        #pragma unroll
        for (int ks = 0; ks < 2; ++ks) {
            half8 af[4], bf[4];
            #pragma unroll
            for (int t = 0; t < 4; ++t) {
                af[t] = *(const half8*)(As + (wm + t * 16 + lr) * 64 + (((ks * 4 + lq) ^ (lr & 7)) * 8));
                bf[t] = *(const half8*)(Bs + (wn + t * 16 + lr) * 64 + (((ks * 4 + lq) ^ (lr & 7)) * 8));
            }
            #pragma unroll
            for (int mt = 0; mt < 4; ++mt)
                #pragma unroll
                for (int nt = 0; nt < 4; ++nt)
                    acc[mt][nt] = __builtin_amdgcn_mfma_f32_16x16x32_f16(
                        af[mt], bf[nt], acc[mt][nt], 0, 0, 0);
        }
    }

    // n-segment is uniform per block (128 | 1024)
    const int seg = (OUT_MODE == 3) ? (n0 >> 10) : 0;
    const float* bp = (OUT_MODE == 3) ? (seg == 0 ? b0 : (seg == 1 ? b1 : b2)) : b0;

    #pragma unroll
    for (int mt = 0; mt < 4; ++mt) {
        const int row = m0 + wm + mt * 16 + lq * 4;   // + r
        #pragma unroll
        for (int nt = 0; nt < 4; ++nt) {
            const int col = n0 + wn + nt * 16 + lr;
            const int cl  = (OUT_MODE == 3) ? (col & 1023) : col;
            const float bb = bp[cl];
            if (OUT_MODE == 3 && seg == 2) {
                // V^T per head: [(b*16+h)][hd][s]; 4 consecutive s -> one 8B store
                const int b = row >> 11, sq = row & 2047;
                const int h = cl >> 6, hd = cl & 63;
                half4v o;
                #pragma unroll
                for (int r = 0; r < 4; ++r) {
                    float v = acc[mt][nt][r] + bb;
                    o[r] = (_Float16)(v > 0.0f ? v : 0.0f);
                }
                *(half4v*)((_Float16*)C2 +
                           ((size_t)(b * 16 + h) * 64 + hd) * S_ + sq) = o;
            } else if (OUT_MODE == 3) {
                _Float16* dst = (_Float16*)(seg ? C1 : C0);
                #pragma unroll
                for (int r = 0; r < 4; ++r) {
                    float v = acc[mt][nt][r] + bb;
                    dst[(size_t)(row + r) * 1024 + cl] = (_Float16)(v > 0.0f ? v : 0.0f);
                }
            } else {
                #pragma unroll
                for (int r = 0; r < 4; ++r) {
                    float v = acc[mt][nt][r] + bb;
                    ((float*)C0)[(size_t)(row + r) * N + col] = v > 0.0f ? v : 0.0f;
                }
            }
        }
    }
}

// ---------------- flash attention (4 frags/wave + in-register P) ----------------
// R11: combine the two proven halves.
//  - R9 (75.6us): 4 frags/wave, 512 blocks -> per-tile fixed costs (2 barriers,
//    kf/bv LDS reads, issue_tile) amortized over ~2.6 active frags. R2's
//    2-frag/1024-block variant doubled tile-iterations (12.8k -> 25k) and
//    regressed to 80.5us despite higher occupancy.
//  - R2: in-register P. QK^T output (lane lr=q, 16 strided k) -> PV A-operand
//    layout (k=32ks+8lq+j) via permlane32_swap+permlane16_swap per lq-group.
//    Verified: bank conflicts 2.16M -> 0, no P-LDS (32 KB total), no
//    lgkmcnt(0) serialization point mid-tile.
// Phases merged (kf+bv read once per tile), per-frag {QK -> softmax ->
// permlane -> PV} so frag f's VALU overlaps frag f+1's MFMA. setprio(1)
// around MFMA clusters (T5). launch_bounds(256,2): grid 512 = 2 blocks/CU
// regardless, so allow full 256-reg budget (live set ~220; R1 showed a
// 128-reg cap spills catastrophically).
__global__ __launch_bounds__(256, 2) void attn_kernel(
    const _Float16* __restrict__ Qg, const _Float16* __restrict__ Kg,
    const _Float16* __restrict__ Vtg, _Float16* __restrict__ Y)
{
    __shared__ _Float16 Ks[2][64 * 64];      // [key][hd], swizzled chunks
    __shared__ _Float16 Vt[2][64 * 64];      // [hd][key], swizzled chunks

    // XCD swizzle: a head's 8 blocks share (i&7) -> same XCD L2 caches its K/V.
    const int i  = blockIdx.x;                 // 0..511
    const int bh = ((i & 7) << 3) | (i >> 6);  // 0..63
    const int p  = (i >> 3) & 7;               // pair index 0..7
    const int b  = bh >> 4, h = bh & 15;
    const int tid = threadIdx.x, wid = tid >> 6, lane = tid & 63;
    const int lr = lane & 15, lq = lane >> 4;

    const size_t base  = ((size_t)b * S_) * D_ + (size_t)h * HD_;   // Q/K/Y
    const _Float16* Vh = Vtg + (size_t)bh * 64 * S_;                // V^T head

    const int srow = tid >> 3;                       // 0..31
    const int csw  = ((tid & 7) ^ (srow & 7)) * 8;   // swizzled SOURCE col (halfs)

    // 4 fragments per wave: 2 from lo tile (rows 128p+), 2 from hi (1920-128p+)
    const int L = 128 * p, Hh = 1920 - 128 * p;
    const int qb[4] = { L + 16 * wid, L + 64 + 16 * wid,
                        Hh + 16 * wid, Hh + 64 + 16 * wid };
    const int dk[4] = { 2 * p, 2 * p + 1, 30 - 2 * p, 31 - 2 * p };  // diag k-tile
    const int nIter = 32 - 2 * p;

    // Q fragments (B-operand rows [q][hd]) pre-scaled by log2(e)/8
    half8 aq[4][2];
    #pragma unroll
    for (int f = 0; f < 4; ++f) {
        const _Float16* qp = Qg + base + (size_t)(qb[f] + lr) * D_;
        aq[f][0] = hscale8(*(const half8*)(qp + lq * 8),      (_Float16)0.18033688f);
        aq[f][1] = hscale8(*(const half8*)(qp + 32 + lq * 8), (_Float16)0.18033688f);
    }

    float lsum[4] = {};
    f32x4 O[4][4] = {};

    auto issue_tile = [&](int kb) {
        const int bufi = kb & 1;
        #pragma unroll
        for (int ii = 0; ii < 2; ++ii) {
            async_copy16(Kg + base + (size_t)(kb * 64 + ii * 32 + srow) * D_ + csw,
                         (char*)Ks[bufi] + (ii * 256 + wid * 64) * 16);
            async_copy16(Vh + (size_t)(ii * 32 + srow) * S_ + kb * 64 + csw,
                         (char*)Vt[bufi] + (ii * 256 + wid * 64) * 16);
        }
    };

    issue_tile(0);

    for (int kb = 0; kb < nIter; ++kb) {
        const int cur = kb & 1;
        __syncthreads();   // buf[cur] loads done; all waves done with buf[cur] from kb-2
        if (kb + 1 < nIter) issue_tile(kb + 1);

        const _Float16* Kc = Ks[cur];
        const _Float16* Vc = Vt[cur];

        // read kf (K rows) and bv (V^T rows) ONCE per tile, shared by all frags
        half8 kf[2][4], bv[2][4];
        #pragma unroll
        for (int ks = 0; ks < 2; ++ks)
            #pragma unroll
            for (int tt = 0; tt < 4; ++tt) {
                kf[ks][tt] = *(const half8*)(Kc + (tt * 16 + lr) * 64 + (((ks * 4 + lq) ^ (lr & 7)) * 8));
                bv[ks][tt] = *(const half8*)(Vc + (tt * 16 + lr) * 64 + (((ks * 4 + lq) ^ (lr & 7)) * 8));
            }

        #pragma unroll
        for (int f = 0; f < 4; ++f) {
            if (kb > dk[f]) continue;            // frag done (wave-uniform)

            // ---- QK^T ----
            f32x4 sc[4] = {};
            __builtin_amdgcn_s_setprio(1);
            #pragma unroll
            for (int ks = 0; ks < 2; ++ks)
                #pragma unroll
                for (int tt = 0; tt < 4; ++tt)
                    sc[tt] = __builtin_amdgcn_mfma_f32_16x16x32_f16(kf[ks][tt], aq[f][ks], sc[tt], 0, 0, 0);
            __builtin_amdgcn_s_setprio(0);

            // ---- softmax (fixed normalizer, log2 domain) ----
            const bool diag = (kb == dk[f]);     // wave-uniform
            const int qg = qb[f] + lr;           // this lane's q
            const int kbase = kb * 64 + lq * 4;
            float sum = 0.0f;
            unsigned int pk[4][2];               // pk[t][d]: packed f16x2 of ev
            #pragma unroll
            for (int tt = 0; tt < 4; ++tt) {
                float ev[4];
                #pragma unroll
                for (int r = 0; r < 4; ++r) {
                    // sc in log2 units; 4*log2e = 5.770780, clamp 11*log2e
                    float e = __builtin_amdgcn_exp2f(fminf(sc[tt][r] - 5.770780f, 15.8696f));
                    if (diag)
                        e = (kbase + tt * 16 + r <= qg) ? e : 0.0f;  // causal AFTER exp
                    ev[r] = e;
                    sum += e;
                }
                pk[tt][0] = pack2(ev[0], ev[1]);
                pk[tt][1] = pack2(ev[2], ev[3]);
            }
            lsum[f] += sum;

            // ---- in-register layout exchange (per 4-lane lq-group) ----
            // permlane32_swap: a'=[a0,a1,b0,b1], b'=[a2,a3,b2,b3] (16-lane rows)
            // permlane16_swap: a''=[a0,b0,a2,b2], b''=[a1,b1,a3,b3]
            half8 ap[2];
            #pragma unroll
            for (int ks = 0; ks < 2; ++ks) {
                uint2v s1 = __builtin_amdgcn_permlane32_swap(pk[2 * ks][0], pk[2 * ks + 1][0], false, false);
                uint2v s2 = __builtin_amdgcn_permlane16_swap(s1[0], s1[1], false, false);
                uint2v u1 = __builtin_amdgcn_permlane32_swap(pk[2 * ks][1], pk[2 * ks + 1][1], false, false);
                uint2v u2 = __builtin_amdgcn_permlane16_swap(u1[0], u1[1], false, false);
                uint4v d = { s2[0], u2[0], s2[1], u2[1] };
                ap[ks] = __builtin_bit_cast(half8, d);
            }

            // ---- PV ----
            __builtin_amdgcn_s_setprio(1);
            #pragma unroll
            for (int ks = 0; ks < 2; ++ks)
                #pragma unroll
                for (int tt = 0; tt < 4; ++tt)
                    O[f][tt] = __builtin_amdgcn_mfma_f32_16x16x32_f16(ap[ks], bv[ks][tt], O[f][tt], 0, 0, 0);
            __builtin_amdgcn_s_setprio(0);
        }
    }

    // epilogue: combine lq-group partial sums, then ctx = O/(l+EPS) -> Y f16
    #pragma unroll
    for (int f = 0; f < 4; ++f) {
        float tot = lsum[f];
        tot += __shfl_xor(tot, 16);
        tot += __shfl_xor(tot, 32);          // all 4 copies of q=lr now hold row sum
        const int q0 = qb[f] + lq * 4;
        #pragma unroll
        for (int r = 0; r < 4; ++r) {
            const float inv = 1.0f / (__shfl(tot, lq * 4 + r) + 1e-7f);
            #pragma unroll
            for (int nt = 0; nt < 4; ++nt)
                Y[base + (size_t)(q0 + r) * D_ + nt * 16 + lr] = (_Float16)(O[f][nt][r] * inv);
        }
    }
}

// ---------------- launch ----------------

extern "C" void kernel_launch(void* const* d_in, const int* in_sizes, int n_in,
                              void* d_out, int out_size, void* d_ws, size_t ws_size,
                              hipStream_t stream) {
    const float* x  = (const float*)d_in[0];
    const float* Wq = (const float*)d_in[1];
    const float* bq = (const float*)d_in[2];
    const float* Wk = (const float*)d_in[3];
    const float* bk = (const float*)d_in[4];
    const float* Wv = (const float*)d_in[5];
    const float* bv = (const float*)d_in[6];
    const float* Wo = (const float*)d_in[7];
    const float* bo = (const float*)d_in[8];

    // workspace layout (f16): xh 16MB | 4x Wt 2MB (wtq/wtk/wtv contiguous!) |
    // Q,K,Vt,Y 16MB each => 92.3 MB
    char* ws = (char*)d_ws;
    _Float16* xh  = (_Float16*)ws;
    _Float16* wtq = (_Float16*)(ws + (size_t)16777216);
    _Float16* wtk = wtq + 1048576;
    _Float16* wtv = wtk + 1048576;
    _Float16* wto = wtv + 1048576;
    _Float16* Qh  = (_Float16*)(ws + (size_t)16777216 + 4 * (size_t)2097152);
    _Float16* Kh  = Qh + 8388608;
    _Float16* Vth = Kh + 8388608;
    _Float16* Yh  = Vth + 8388608;
    float* out = (float*)d_out;

    cast_x_kernel<<<8192, 256, 0, stream>>>((const float4*)x, (half4v*)xh, 2097152);
    transpose_cast4_kernel<<<dim3(32, 32, 4), dim3(32, 8), 0, stream>>>(
        Wq, Wk, Wv, Wo, wtq, wtk, wtv, wto);

    // fused QKV GEMM: Bt = [wtq;wtk;wtv] (contiguous), N=3072
    gemm_bt_kernel<3><<<dim3(64, 24), 256, 0, stream>>>(
        xh, wtq, bq, bk, bv, Qh, Kh, Vth, 8192, 3072, 1024);

    attn_kernel<<<512, 256, 0, stream>>>(Qh, Kh, Vth, Yh);

    gemm_bt_kernel<0><<<dim3(64, 8), 256, 0, stream>>>(
        Yh, wto, bo, bo, bo, out, out, out, 8192, 1024, 1024);
}